// Round 11
// baseline (116.281 us; speedup 1.0000x reference)
//
#include <hip/hip_runtime.h>
#include <hip/hip_bf16.h>
#include <stdint.h>

#define H 512
#define S 256
#define B 32
#define R 16
#define NEG -1000000000000.0f

typedef unsigned short u16;
typedef short short8 __attribute__((ext_vector_type(8)));
typedef float f32x4 __attribute__((ext_vector_type(4)));

__device__ __forceinline__ float bf2f(u16 u) {
  unsigned int v = ((unsigned int)u) << 16;
  float f; __builtin_memcpy(&f, &v, 4); return f;
}
__device__ __forceinline__ u16 f2u(float x) {
  __hip_bfloat16 h = __float2bfloat16(x);
  u16 u; __builtin_memcpy(&u, &h, 2); return u;
}
__device__ __forceinline__ float ftanh(float x) {
  float e = __expf(2.f * x);
  return 1.f - 2.f * __builtin_amdgcn_rcpf(e + 1.f);
}
// Pade(5,4) tanh
__device__ __forceinline__ float ptanh(float x) {
  float xc = fminf(4.f, fmaxf(-4.f, x));
  float x2 = xc * xc;
  float num = xc * (945.f + x2 * (105.f + x2));
  float den = 945.f + x2 * (420.f + 15.f * x2);
  return num * __builtin_amdgcn_rcpf(den);
}
__device__ __forceinline__ float fsig(float x) {
  return __builtin_amdgcn_rcpf(1.f + __expf(-x));
}
__device__ __forceinline__ void gload16(const void* g, void* l) {
  __builtin_amdgcn_global_load_lds(
      (const __attribute__((address_space(1))) unsigned int*)g,
      (__attribute__((address_space(3))) unsigned int*)l, 16, 0, 0);
}

// ---------- trans tile helper ----------
__device__ __forceinline__ void trans_tile(const float* __restrict__ src, int nb, int k0,
                                           u16* __restrict__ dst, int n0, int Krows,
                                           float (*tile)[65], int t) {
  #pragma unroll
  for (int it = 0; it < 16; ++it) {
    int f = it * 256 + t; int r = f >> 6, c = f & 63;
    tile[r][c] = src[(size_t)(k0 + r) * 512 + nb + c];
  }
  __syncthreads();
  #pragma unroll
  for (int it = 0; it < 16; ++it) {
    int f = it * 256 + t; int r = f >> 6, c = f & 63;
    dst[(size_t)(n0 + r) * Krows + k0 + c] = f2u(tile[c][r]);
  }
}

// ---------- mega prep ----------
__global__ __launch_bounds__(256) void k_prep1(
    const float* __restrict__ enc, u16* __restrict__ encb, u16* __restrict__ encc,
    const float* __restrict__ Wattn, const float* __restrict__ Wfattn, u16* __restrict__ Wt,
    const float* __restrict__ Wscore, u16* __restrict__ Wt2a, u16* __restrict__ Wt2b,
    const float* __restrict__ Wfp1, u16* __restrict__ Wt3,
    u16* __restrict__ Wt4,
    const float* __restrict__ node_emb, const float* __restrict__ left,
    const int* __restrict__ has_left,
    const float* __restrict__ Wcl, const float* __restrict__ Wclg,
    const float* __restrict__ Wcr, const float* __restrict__ Wcrg,
    float* __restrict__ gp1, float* __restrict__ gp2,
    const float* __restrict__ emb_w, const float* __restrict__ num_pades,
    float* __restrict__ out_embw, u16* __restrict__ embb, u16* __restrict__ leafb) {
  __shared__ float tile[64][65];
  __shared__ float x[128];
  int id = blockIdx.x, t = threadIdx.x;
  if (id < 2048) {
    int i = (id * 256 + t) * 8;
    float4 a = *(const float4*)(enc + i);
    float4 b4 = *(const float4*)(enc + i + 4);
    short8 o;
    o[0] = (short)f2u(a.x); o[1] = (short)f2u(a.y); o[2] = (short)f2u(a.z); o[3] = (short)f2u(a.w);
    o[4] = (short)f2u(b4.x); o[5] = (short)f2u(b4.y); o[6] = (short)f2u(b4.z); o[7] = (short)f2u(b4.w);
    *(short8*)(encb + i) = o;
    int s = i >> 14, b = (i >> 9) & 31, h = i & 511;
    *(short8*)(encc + (((size_t)b << 8) + s) * 512 + h) = o;
  } else if (id < 2176) {            // Wt: [We | Wfe] -> [1024][512]
    int f = id - 2048; int gx = f & 15, gy = f >> 4;
    int n0 = gx * 64, k0 = gy * 64;
    const float* src = (n0 < 512) ? (Wattn + 512 * 512) : Wfattn;
    int nb = (n0 < 512) ? n0 : n0 - 512;
    trans_tile(src, nb, k0, Wt, n0, 512, tile, t);
  } else if (id < 2240) {            // Wt2a: Wscore[1024:]^T [512][512]
    int f = id - 2176; int gx = f & 7, gy = f >> 3;
    trans_tile(Wscore + 1024 * 512, gx * 64, gy * 64, Wt2a, gx * 64, 512, tile, t);
  } else if (id < 2368) {            // Wt2b: Wscore[:1024]^T [512][1024]
    int f = id - 2240; int gx = f & 7, gy = f >> 3;
    trans_tile(Wscore, gx * 64, gy * 64, Wt2b, gx * 64, 1024, tile, t);
  } else if (id < 2432) {            // Wt3: Wfp1^T [512][512]
    int f = id - 2368; int gx = f & 7, gy = f >> 3;
    trans_tile(Wfp1, gx * 64, gy * 64, Wt3, gx * 64, 512, tile, t);
  } else if (id < 2560) {            // Wt4: [Wh^T | Wff^T] -> [1024][512]
    int f = id - 2432; int gx = f & 15, gy = f >> 4;
    int n0 = gx * 64, k0 = gy * 64;
    const float* src = (n0 < 512) ? Wattn : (Wfattn + 512 * 512);
    int nb = (n0 < 512) ? n0 : n0 - 512;
    trans_tile(src, nb, k0, Wt4, n0, 512, tile, t);
  } else if (id < 2816) {            // gates partials
    int f = id - 2560;
    int b = f >> 3, kc = f & 7;
    int hl = has_left[b];
    int k0 = kc * 128;
    float* o1 = gp1 + ((size_t)b * 8 + kc) * 512;
    float* o2 = gp2 + ((size_t)b * 8 + kc) * 512;
    if (!hl && kc >= 4) { o1[t] = 0.f; o1[t + 256] = 0.f; o2[t] = 0.f; o2[t + 256] = 0.f; return; }
    if (t < 128) {
      int k = k0 + t;
      x[t] = hl ? (k < 512 ? left[b * 512 + k] : node_emb[b * 512 + k - 512])
                : node_emb[b * 512 + k];
    }
    __syncthreads();
    const float* W1 = hl ? Wcr : Wcl;
    const float* W2 = hl ? Wcrg : Wclg;
    float a1 = 0.f, a2 = 0.f, a3 = 0.f, a4 = 0.f;
    for (int kk = 0; kk < 128; ++kk) {
      float xv = x[kk];
      const float* w1r = W1 + (size_t)(k0 + kk) * 512;
      const float* w2r = W2 + (size_t)(k0 + kk) * 512;
      a1 += xv * w1r[t]; a2 += xv * w1r[t + 256];
      a3 += xv * w2r[t]; a4 += xv * w2r[t + 256];
    }
    o1[t] = a1; o1[t + 256] = a2; o2[t] = a3; o2[t + 256] = a4;
  } else if (id < 3136) {            // out_embw + embb
    int f = id - 2816;
    #pragma unroll
    for (int rr = 0; rr < 2; ++rr) {
      int row = f * 2 + rr;
      int n = row % 20, b = row / 20;
      #pragma unroll
      for (int i = 0; i < 2; ++i) {
        int h = t + 256 * i;
        float v = (n < 4) ? emb_w[n * 512 + h] : num_pades[((size_t)b * 16 + n - 4) * 512 + h];
        out_embw[(size_t)row * 512 + h] = v;
        embb[(size_t)row * 512 + h] = f2u(v);
      }
    }
  } else {                           // leafb zero-pad rows 32..63
    int f = id - 3136;               // f < 8
    int base = 32 * 1024 + (f * 256 + t) * 16;
    short8 z8 = {0,0,0,0,0,0,0,0};
    *(short8*)(leafb + base) = z8;
    *(short8*)(leafb + base + 8) = z8;
  }
}

// ---------- GEMM device body ----------
template <int FM, int FN>
__device__ __forceinline__ void gemm_body(
    const u16* __restrict__ A, const u16* __restrict__ Bt,
    u16* __restrict__ C16, float* __restrict__ C32,
    int lda, int ldb, int ldc, int ksteps,
    int bm, int bn, int kbase, long zoff,
    u16* As, u16* Bs) {
  constexpr int BM = FM * 32, BN = FN * 32;
  const int tid = threadIdx.x;
  const int lane = tid & 63;
  const int wid = tid >> 6;
  const int wr = (wid >> 1) * (FM * 16);
  const int wc = (wid & 1) * (FN * 16);
  f32x4 acc[FM][FN];
  #pragma unroll
  for (int m = 0; m < FM; ++m)
    #pragma unroll
    for (int n = 0; n < FN; ++n)
      #pragma unroll
      for (int q = 0; q < 4; ++q) acc[m][n][q] = 0.f;

  const int kb = (lane >> 4) * 8;
  const int rr = lane & 15;
  for (int ks = 0; ks < ksteps; ++ks) {
    int k0 = kbase + ks * 32;
    #pragma unroll
    for (int it = 0; it < BM / 64; ++it) {
      int c = it * 256 + tid;
      gload16(A + (size_t)(bm + (c >> 2)) * lda + k0 + (c & 3) * 8, As + c * 8);
    }
    #pragma unroll
    for (int it = 0; it < BN / 64; ++it) {
      int c = it * 256 + tid;
      gload16(Bt + (size_t)(bn + (c >> 2)) * ldb + k0 + (c & 3) * 8, Bs + c * 8);
    }
    __syncthreads();
    short8 af[FM], bf[FN];
    #pragma unroll
    for (int m = 0; m < FM; ++m)
      af[m] = *(const short8*)(As + (wr + m * 16 + rr) * 32 + kb);
    #pragma unroll
    for (int n = 0; n < FN; ++n)
      bf[n] = *(const short8*)(Bs + (wc + n * 16 + rr) * 32 + kb);
    #pragma unroll
    for (int m = 0; m < FM; ++m)
      #pragma unroll
      for (int n = 0; n < FN; ++n)
        acc[m][n] = __builtin_amdgcn_mfma_f32_16x16x32_bf16(af[m], bf[n], acc[m][n], 0, 0, 0);
    __syncthreads();
  }
  int r0 = (lane >> 4) * 4, cc = lane & 15;
  #pragma unroll
  for (int m = 0; m < FM; ++m)
    #pragma unroll
    for (int n = 0; n < FN; ++n)
      #pragma unroll
      for (int q = 0; q < 4; ++q) {
        long row = bm + wr + m * 16 + r0 + q;
        long col = bn + wc + n * 16 + cc;
        if (C16) C16[zoff + row * ldc + col] = f2u(acc[m][n][q]);
        else     C32[zoff + row * ldc + col] = acc[m][n][q];
      }
}

// ---------- G1: EW GEMM (512) + CWFW GEMM (8) + T_emb GEMM (160, z=2) ----------
__global__ __launch_bounds__(256) void k_g1(
    const u16* __restrict__ encb, const u16* __restrict__ Wt, u16* __restrict__ EW,
    const u16* __restrict__ cnfs, const u16* __restrict__ Wt4, float* __restrict__ CWFW,
    const u16* __restrict__ embb, const u16* __restrict__ Wt2a, float* __restrict__ Tep) {
  __shared__ u16 As[128 * 32];
  __shared__ u16 Bs[128 * 32];
  int q = blockIdx.x;
  if (q < 512) {
    int x = q & 63, y = q >> 6;
    gemm_body<4, 4>(encb, Wt, EW, nullptr, 512, 512, 1024, 16, x * 128, y * 128, 0, 0, As, Bs);
  } else if (q < 520) {
    int y = q - 512;
    gemm_body<4, 4>(cnfs, Wt4, nullptr, CWFW, 512, 512, 1024, 16, 0, y * 128, 0, 0, As, Bs);
  } else {                      // T_emb: 640x512 @ K=512, z=2
    int q2 = q - 520;
    int x = q2 % 10, y = (q2 / 10) % 8, z = q2 / 80;
    gemm_body<2, 2>(embb, Wt2a, nullptr, Tep, 512, 512, 512, 8,
                    x * 64, y * 64, z * 8 * 32, (long)z * 327680, As, Bs);
  }
}

// ---------- tt: T_leaf (16, z=2) + T3 (128, z=2) GEMMs + op reduce (192) ----------
__global__ __launch_bounds__(256) void k_tt(
    const u16* __restrict__ leafb, const u16* __restrict__ Wt2b, float* __restrict__ Tlp,
    const u16* __restrict__ fctxb, const u16* __restrict__ Wt3, float* __restrict__ T3p,
    const float* __restrict__ leaf, const float* __restrict__ Wops,
    const float* __restrict__ bops, float* __restrict__ out_op) {
  __shared__ u16 As[64 * 32];
  __shared__ u16 Bs[64 * 32];
  __shared__ float red[4];
  int q = blockIdx.x;
  if (q < 16) {                  // T_leaf: 64x512 @ K=1024, z=2
    int y = q % 8, z = q / 8;
    gemm_body<2, 2>(leafb, Wt2b, nullptr, Tlp, 1024, 1024, 512, 16,
                    0, y * 64, z * 16 * 32, (long)z * 32768, As, Bs);
  } else if (q < 144) {          // T3: 512x512 @ K=512, z=2
    int q2 = q - 16;
    int x = q2 % 8, y = (q2 / 8) % 8, z = q2 / 64;
    gemm_body<2, 2>(fctxb, Wt3, nullptr, T3p, 512, 512, 512, 8,
                    x * 64, y * 64, z * 8 * 32, (long)z * 262144, As, Bs);
  } else {                       // op reduce
    int f = q - 144; int o = f % 6, b = f / 6;
    int t = threadIdx.x, w = t >> 6, lane = t & 63;
    float acc = 0.f;
    #pragma unroll
    for (int i = 0; i < 4; ++i) {
      int k = t + 256 * i;
      acc += leaf[b * 1024 + k] * Wops[(size_t)k * 6 + o];
    }
    for (int off = 32; off >= 1; off >>= 1) acc += __shfl_down(acc, off);
    if (lane == 0) red[w] = acc;
    __syncthreads();
    if (t == 0) out_op[b * 6 + o] = red[0] + red[1] + red[2] + red[3] + bops[o];
  }
}

// ---------- p2lite: finish gates -> cur_node/out_cn/cnfs; fs rows; zero pad ----------
__global__ __launch_bounds__(256) void k_p2(
    const float* __restrict__ gp1, const float* __restrict__ gp2,
    const int* __restrict__ has_left,
    const float* __restrict__ bcl, const float* __restrict__ bclg,
    const float* __restrict__ bcr, const float* __restrict__ bcrg,
    const float* __restrict__ fs,
    float* __restrict__ cur_node, float* __restrict__ out_cn, u16* __restrict__ cnfs) {
  int id = blockIdx.x, t = threadIdx.x;
  if (id < 32) {
    int b = id, hl = has_left[b];
    #pragma unroll
    for (int i = 0; i < 2; ++i) {
      int h = t + 256 * i;
      float s1 = 0.f, s2 = 0.f;
      #pragma unroll
      for (int c = 0; c < 8; ++c) {
        s1 += gp1[((size_t)b * 8 + c) * 512 + h];
        s2 += gp2[((size_t)b * 8 + c) * 512 + h];
      }
      float v = ftanh(s1 + (hl ? bcr[h] : bcl[h])) * fsig(s2 + (hl ? bcrg[h] : bclg[h]));
      cur_node[b * 512 + h] = v;
      out_cn[b * 512 + h] = v;
      cnfs[b * 512 + h] = f2u(v);
    }
  } else if (id < 48) {
    int r = id - 32;
    #pragma unroll
    for (int i = 0; i < 2; ++i) {
      int h = t + 256 * i;
      cnfs[id * 512 + h] = f2u(fs[r * 512 + h]);
    }
  } else {
    #pragma unroll
    for (int i = 0; i < 2; ++i) cnfs[id * 512 + t + 256 * i] = 0;
  }
}

// ---------- en + fen fused (mask-skip, 4 s per wave) ----------
__global__ __launch_bounds__(256) void k_enfen(
    const u16* __restrict__ EW, const float* __restrict__ CWFW,
    const float* __restrict__ battn, const float* __restrict__ bfattn,
    const float* __restrict__ wattn_s, const float* __restrict__ battn_s,
    const float* __restrict__ wfattn_s, const float* __restrict__ bfattn_s,
    const int* __restrict__ seq_mask, float* __restrict__ en, float* __restrict__ fen) {
  __shared__ float sFW[16 * 512];
  __shared__ float swf[512], swa[512], scw[512];
  int bid = blockIdx.x;          // 512 = 32 b * 16 s-chunks of 16
  int b = bid >> 4;
  int s0 = (bid & 15) * 16;
  int t = threadIdx.x;
  #pragma unroll
  for (int q = 0; q < 32; ++q) {
    int flat = q * 256 + t;
    int r = flat >> 9, h = flat & 511;
    sFW[flat] = CWFW[(size_t)(32 + r) * 1024 + 512 + h] + bfattn[h];
  }
  swf[t] = wfattn_s[t]; swf[256 + t] = wfattn_s[256 + t];
  swa[t] = wattn_s[t];  swa[256 + t] = wattn_s[256 + t];
  scw[t] = CWFW[(size_t)b * 1024 + t] + battn[t];
  scw[256 + t] = CWFW[(size_t)b * 1024 + 256 + t] + battn[256 + t];
  __syncthreads();
  int w = t >> 6, lane = t & 63;
  int sbase = s0 + w * 4;
  int msk[4];
  int allm = 1;
  #pragma unroll
  for (int p = 0; p < 4; ++p) { msk[p] = seq_mask[b * 256 + sbase + p]; allm &= msk[p]; }
  if (allm) {
    if (lane == 0) {
      #pragma unroll
      for (int p = 0; p < 4; ++p) en[b * 256 + sbase + p] = NEG;
      for (int r = 0; r < 16; ++r)
        #pragma unroll
        for (int p = 0; p < 4; ++p)
          fen[((size_t)b * 16 + r) * 256 + sbase + p] = NEG;
    }
    return;
  }
  const u16* ew[4];
  #pragma unroll
  for (int p = 0; p < 4; ++p) ew[p] = EW + (size_t)((sbase + p) * 32 + b) * 1024;
  float ewf[4][8], wfv[8];
  float accE[4] = {0.f, 0.f, 0.f, 0.f};
  #pragma unroll
  for (int i = 0; i < 8; ++i) {
    int h = lane + 64 * i;
    float cw = scw[h], wa = swa[h];
    #pragma unroll
    for (int p = 0; p < 4; ++p) {
      accE[p] += ptanh(cw + bf2f(ew[p][h])) * wa;
      ewf[p][i] = bf2f(ew[p][512 + h]);
    }
    wfv[i] = swf[h];
  }
  for (int o = 32; o >= 1; o >>= 1) {
    #pragma unroll
    for (int p = 0; p < 4; ++p) accE[p] += __shfl_down(accE[p], o);
  }
  if (lane == 0) {
    #pragma unroll
    for (int p = 0; p < 4; ++p)
      en[b * 256 + sbase + p] = msk[p] ? NEG : (accE[p] + battn_s[0]);
  }
  for (int r = 0; r < 16; ++r) {
    float a[4] = {0.f, 0.f, 0.f, 0.f};
    #pragma unroll
    for (int i = 0; i < 8; ++i) {
      int h = lane + 64 * i;
      float fwv = sFW[r * 512 + h];
      float wf = wfv[i];
      #pragma unroll
      for (int p = 0; p < 4; ++p) a[p] += ptanh(fwv + ewf[p][i]) * wf;
    }
    for (int o = 32; o >= 1; o >>= 1) {
      #pragma unroll
      for (int p = 0; p < 4; ++p) a[p] += __shfl_down(a[p], o);
    }
    if (lane == 0) {
      #pragma unroll
      for (int p = 0; p < 4; ++p)
        fen[((size_t)b * 16 + r) * 256 + sbase + p] = msk[p] ? NEG : (a[p] + bfattn_s[0]);
    }
  }
}

// ---------- softmaxes + contexts, j-quad (5 blocks per b), contiguous encc ----------
__global__ __launch_bounds__(512) void k_ctxall(
    const float* __restrict__ en, const float* __restrict__ fen,
    const u16* __restrict__ encc, const float* __restrict__ cur_node,
    float* __restrict__ out_ctx, float* __restrict__ leaf, u16* __restrict__ fctxb,
    u16* __restrict__ leafb) {
  int br = blockIdx.x;           // 160 = 32 * 5
  int b = br / 5, k = br % 5;
  int t = threadIdx.x;
  __shared__ float red[512];
  __shared__ float sa[4][256];
  float xe = (t < 256) ? en[b * 256 + t] : NEG;
  red[t] = xe; __syncthreads();
  for (int o = 256; o > 0; o >>= 1) { if (t < o) red[t] = fmaxf(red[t], red[t + o]); __syncthreads(); }
  float m = red[0]; __syncthreads();
  float ee = (t < 256) ? __expf(xe - m) : 0.f;
  red[t] = ee; __syncthreads();
  for (int o = 256; o > 0; o >>= 1) { if (t < o) red[t] += red[t + o]; __syncthreads(); }
  float attn_v = ee / red[0];
  __syncthreads();
  const u16* eb = encc + (size_t)b * 131072;
  if (k < 4) {
    #pragma unroll
    for (int p = 0; p < 4; ++p) {
      int j = k + p * 4;
      float xf = (t < 256) ? fen[((size_t)b * 16 + j) * 256 + t] : NEG;
      red[t] = xf; __syncthreads();
      for (int o = 256; o > 0; o >>= 1) { if (t < o) red[t] = fmaxf(red[t], red[t + o]); __syncthreads(); }
      float mf = red[0]; __syncthreads();
      float ef = (t < 256) ? __expf(xf - mf) : 0.f;
      red[t] = ef; __syncthreads();
      for (int o = 256; o > 0; o >>= 1) { if (t < o) red[t] += red[t + o]; __syncthreads(); }
      float coef = ef / red[0] + 0.2f * attn_v;
      __syncthreads();
      if (t < 256) sa[p][t] = coef;
    }
    __syncthreads();
    int h = t;
    float acc0 = 0.f, acc1 = 0.f, acc2 = 0.f, acc3 = 0.f;
    #pragma unroll 4
    for (int s = 0; s < 256; ++s) {
      float ev = bf2f(eb[(size_t)s * 512 + h]);
      acc0 += sa[0][s] * ev;
      acc1 += sa[1][s] * ev;
      acc2 += sa[2][s] * ev;
      acc3 += sa[3][s] * ev;
    }
    fctxb[((size_t)b * 16 + k) * 512 + h] = f2u(acc0);
    fctxb[((size_t)b * 16 + k + 4) * 512 + h] = f2u(acc1);
    fctxb[((size_t)b * 16 + k + 8) * 512 + h] = f2u(acc2);
    fctxb[((size_t)b * 16 + k + 12) * 512 + h] = f2u(acc3);
  } else {
    if (t < 256) sa[0][t] = attn_v;
    __syncthreads();
    int h = t;
    float acc = 0.f;
    #pragma unroll 8
    for (int s = 0; s < 256; ++s)
      acc += sa[0][s] * bf2f(eb[(size_t)s * 512 + h]);
    float cn = cur_node[b * 512 + h];
    out_ctx[b * 512 + h] = acc;
    leaf[b * 1024 + 512 + h] = acc;
    leaf[b * 1024 + h] = cn;
    leafb[b * 1024 + h] = f2u(cn);
    leafb[b * 1024 + 512 + h] = f2u(acc);
  }
}

// ---------- epilogue: num_score + formula_prob ----------
__global__ __launch_bounds__(256) void k_epi(
    const float* __restrict__ Tep, const float* __restrict__ Tlp,
    const float* __restrict__ bscore,
    const float* __restrict__ wscore_s, const int* __restrict__ mask_nums,
    float* __restrict__ out_ns,
    const float* __restrict__ T3p, const float* __restrict__ bfp1,
    const float* __restrict__ Wfp2, const float* __restrict__ bfp2,
    float* __restrict__ out_fp) {
  int id = blockIdx.x, t = threadIdx.x;
  int w = t >> 6, lane = t & 63;
  __shared__ float red[16];
  if (id < 640) {
    int row = id;
    int b = row / 20;
    float acc = 0.f;
    #pragma unroll
    for (int i = 0; i < 2; ++i) {
      int h = t + 256 * i;
      float tv = bscore[h];
      #pragma unroll
      for (int z = 0; z < 2; ++z) tv += Tep[(size_t)z * 327680 + (size_t)row * 512 + h];
      #pragma unroll
      for (int z = 0; z < 2; ++z) tv += Tlp[(size_t)z * 32768 + (size_t)b * 512 + h];
      acc += ftanh(tv) * wscore_s[h];
    }
    for (int o = 32; o >= 1; o >>= 1) acc += __shfl_down(acc, o);
    if (lane == 0) red[w] = acc;
    __syncthreads();
    if (t == 0) out_ns[row] = mask_nums[row] ? NEG : (red[0] + red[1] + red[2] + red[3]);
  } else {
    int b = id - 640;
    #pragma unroll
    for (int j2 = 0; j2 < 4; ++j2) {
      int j = w * 4 + j2;
      int row = b * 16 + j;
      float acc = 0.f;
      #pragma unroll
      for (int i = 0; i < 8; ++i) {
        int h = lane + 64 * i;
        float v = bfp1[h];
        #pragma unroll
        for (int z = 0; z < 2; ++z) v += T3p[(size_t)z * 262144 + (size_t)row * 512 + h];
        acc += ftanh(v) * Wfp2[h];
      }
      for (int o = 32; o >= 1; o >>= 1) acc += __shfl_down(acc, o);
      if (lane == 0) red[j] = acc + bfp2[0];
    }
    __syncthreads();
    if (t < 16) {
      float xx = red[t];
      float mm = xx;
      for (int o = 8; o >= 1; o >>= 1) mm = fmaxf(mm, __shfl_xor(mm, o, 16));
      float e = __expf(xx - mm);
      float s2 = e;
      for (int o = 8; o >= 1; o >>= 1) s2 += __shfl_xor(s2, o, 16);
      out_fp[b * 16 + t] = e / s2;
    }
  }
}

extern "C" void kernel_launch(void* const* d_in, const int* in_sizes, int n_in,
                              void* d_out, int out_size, void* d_ws, size_t ws_size,
                              hipStream_t stream) {
  const float* node_emb  = (const float*)d_in[0];
  const float* left      = (const float*)d_in[1];
  const float* enc       = (const float*)d_in[2];
  const float* num_pades = (const float*)d_in[3];
  const float* fs        = (const float*)d_in[4];
  const int*   has_left  = (const int*)d_in[5];
  const int*   seq_mask  = (const int*)d_in[6];
  const int*   mask_nums = (const int*)d_in[7];
  const float* emb_w     = (const float*)d_in[8];
  const float* Wcl  = (const float*)d_in[9];
  const float* bcl  = (const float*)d_in[10];
  const float* Wclg = (const float*)d_in[11];
  const float* bclg = (const float*)d_in[12];
  const float* Wcr  = (const float*)d_in[13];
  const float* bcr  = (const float*)d_in[14];
  const float* Wcrg = (const float*)d_in[15];
  const float* bcrg = (const float*)d_in[16];
  const float* Wops = (const float*)d_in[17];
  const float* bops = (const float*)d_in[18];
  const float* Wattn   = (const float*)d_in[19];
  const float* battn   = (const float*)d_in[20];
  const float* wattn_s = (const float*)d_in[21];
  const float* battn_s = (const float*)d_in[22];
  const float* Wfattn   = (const float*)d_in[23];
  const float* bfattn   = (const float*)d_in[24];
  const float* wfattn_s = (const float*)d_in[25];
  const float* bfattn_s = (const float*)d_in[26];
  const float* Wscore   = (const float*)d_in[27];
  const float* bscore   = (const float*)d_in[28];
  const float* wscore_s = (const float*)d_in[29];
  const float* Wfp1 = (const float*)d_in[30];
  const float* bfp1 = (const float*)d_in[31];
  const float* Wfp2 = (const float*)d_in[32];
  const float* bfp2 = (const float*)d_in[33];

  float* out = (float*)d_out;
  float* out_ns   = out + 0;
  float* out_op   = out + 640;
  float* out_cn   = out + 832;
  float* out_ctx  = out + 17216;
  float* out_embw = out + 33600;
  float* out_fp   = out + 361280;

  // ws is 256 MiB
  uint8_t* wsb = (uint8_t*)d_ws;
  u16*   encb = (u16*)(wsb + 0);              //  8,388,608
  u16*   Wt   = (u16*)(wsb + 8388608);        //  1,048,576
  u16*   Wt2a = (u16*)(wsb + 9437184);        //    524,288
  u16*   Wt2b = (u16*)(wsb + 9961472);        //  1,048,576
  u16*   Wt3  = (u16*)(wsb + 11010048);       //    524,288
  u16*   Wt4  = (u16*)(wsb + 11534336);       //  1,048,576
  u16*   EW   = (u16*)(wsb + 12582912);       // 16,777,216
  u16*   embb = (u16*)(wsb + 29360128);       //    655,360
  u16*   leafb= (u16*)(wsb + 30015488);       //    131,072
  u16*   cnfs = (u16*)(wsb + 30146560);       //    131,072
  float* CWFW = (float*)(wsb + 30277632);     //    524,288
  float* Tep  = (float*)(wsb + 30801920);     //  5,242,880 (z=2 uses 2.5MB)
  float* Tlp  = (float*)(wsb + 36044800);     //    524,288
  float* T3p  = (float*)(wsb + 36569088);     //  4,194,304 (z=2 uses 2MB)
  float* fb   = (float*)(wsb + 40763392);
  float* cur_node = fb + 0;          // 16384
  float* en   = fb + 16384;          // 8192
  float* fen  = fb + 24576;          // 131072
  float* leaf = fb + 155648;         // 32768
  u16*   fctxb= (u16*)(fb + 188416); // 262144 u16
  float* gp1  = fb + 319488;         // 131072
  float* gp2  = fb + 450560;         // 131072
  u16*   encc = (u16*)(wsb + 45088768);       //  8,388,608

  // 1. mega prep (inputs only)
  k_prep1<<<3144, 256, 0, stream>>>(enc, encb, encc, Wattn, Wfattn, Wt, Wscore, Wt2a, Wt2b,
                                    Wfp1, Wt3, Wt4,
                                    node_emb, left, has_left, Wcl, Wclg, Wcr, Wcrg,
                                    gp1, gp2, emb_w, num_pades, out_embw, embb, leafb);
  // 2. finish gates -> cur_node + cnfs
  k_p2<<<128, 256, 0, stream>>>(gp1, gp2, has_left, bcl, bclg, bcr, bcrg, fs,
                                cur_node, out_cn, cnfs);
  // 3. G1: EW GEMM + CWFW GEMM + T_emb GEMM (z=2, co-scheduled)
  k_g1<<<680, 256, 0, stream>>>(encb, Wt, EW, cnfs, Wt4, CWFW, embb, Wt2a, Tep);
  // 4. attention scores (mask-skip, 4 s per wave)
  k_enfen<<<512, 256, 0, stream>>>(EW, CWFW, battn, bfattn, wattn_s, battn_s,
                                   wfattn_s, bfattn_s, seq_mask, en, fen);
  // 5. softmaxes + contexts, j-quad, contiguous encc
  k_ctxall<<<160, 512, 0, stream>>>(en, fen, encc, cur_node, out_ctx, leaf, fctxb, leafb);
  // 6. T_leaf + T3 GEMMs (z=2) + op reduce
  k_tt<<<336, 256, 0, stream>>>(leafb, Wt2b, Tlp, fctxb, Wt3, T3p,
                                leaf, Wops, bops, out_op);
  // 7. epilogue: ns + ffprob
  k_epi<<<672, 256, 0, stream>>>(Tep, Tlp, bscore, wscore_s, mask_nums, out_ns,
                                 T3p, bfp1, Wfp2, bfp2, out_fp);
}

// Round 12
// 99.208 us; speedup vs baseline: 1.1721x; 1.1721x over previous
//
#include <hip/hip_runtime.h>
#include <hip/hip_bf16.h>
#include <stdint.h>

#define H 512
#define S 256
#define B 32
#define R 16
#define NEG -1000000000000.0f

typedef unsigned short u16;
typedef short short8 __attribute__((ext_vector_type(8)));
typedef float f32x4 __attribute__((ext_vector_type(4)));

__device__ __forceinline__ float bf2f(u16 u) {
  unsigned int v = ((unsigned int)u) << 16;
  float f; __builtin_memcpy(&f, &v, 4); return f;
}
__device__ __forceinline__ u16 f2u(float x) {
  __hip_bfloat16 h = __float2bfloat16(x);
  u16 u; __builtin_memcpy(&u, &h, 2); return u;
}
__device__ __forceinline__ float ftanh(float x) {
  float e = __expf(2.f * x);
  return 1.f - 2.f * __builtin_amdgcn_rcpf(e + 1.f);
}
// Pade(5,4) tanh
__device__ __forceinline__ float ptanh(float x) {
  float xc = fminf(4.f, fmaxf(-4.f, x));
  float x2 = xc * xc;
  float num = xc * (945.f + x2 * (105.f + x2));
  float den = 945.f + x2 * (420.f + 15.f * x2);
  return num * __builtin_amdgcn_rcpf(den);
}
__device__ __forceinline__ float fsig(float x) {
  return __builtin_amdgcn_rcpf(1.f + __expf(-x));
}
__device__ __forceinline__ void gload16(const void* g, void* l) {
  __builtin_amdgcn_global_load_lds(
      (const __attribute__((address_space(1))) unsigned int*)g,
      (__attribute__((address_space(3))) unsigned int*)l, 16, 0, 0);
}

// ---------- trans tile helper ----------
__device__ __forceinline__ void trans_tile(const float* __restrict__ src, int nb, int k0,
                                           u16* __restrict__ dst, int n0, int Krows,
                                           float (*tile)[65], int t) {
  #pragma unroll
  for (int it = 0; it < 16; ++it) {
    int f = it * 256 + t; int r = f >> 6, c = f & 63;
    tile[r][c] = src[(size_t)(k0 + r) * 512 + nb + c];
  }
  __syncthreads();
  #pragma unroll
  for (int it = 0; it < 16; ++it) {
    int f = it * 256 + t; int r = f >> 6, c = f & 63;
    dst[(size_t)(n0 + r) * Krows + k0 + c] = f2u(tile[c][r]);
  }
}

// ---------- mega prep ----------
__global__ __launch_bounds__(256) void k_prep1(
    const float* __restrict__ enc, u16* __restrict__ encb, u16* __restrict__ encc,
    const float* __restrict__ Wattn, const float* __restrict__ Wfattn, u16* __restrict__ Wt,
    const float* __restrict__ Wscore, u16* __restrict__ Wt2a, u16* __restrict__ Wt2b,
    const float* __restrict__ Wfp1, u16* __restrict__ Wt3,
    u16* __restrict__ Wt4,
    const float* __restrict__ node_emb, const float* __restrict__ left,
    const int* __restrict__ has_left,
    const float* __restrict__ Wcl, const float* __restrict__ Wclg,
    const float* __restrict__ Wcr, const float* __restrict__ Wcrg,
    float* __restrict__ gp1, float* __restrict__ gp2,
    const float* __restrict__ emb_w, const float* __restrict__ num_pades,
    float* __restrict__ out_embw, u16* __restrict__ embb, u16* __restrict__ leafb) {
  __shared__ float tile[64][65];
  __shared__ float x[128];
  int id = blockIdx.x, t = threadIdx.x;
  if (id < 2048) {
    int i = (id * 256 + t) * 8;
    float4 a = *(const float4*)(enc + i);
    float4 b4 = *(const float4*)(enc + i + 4);
    short8 o;
    o[0] = (short)f2u(a.x); o[1] = (short)f2u(a.y); o[2] = (short)f2u(a.z); o[3] = (short)f2u(a.w);
    o[4] = (short)f2u(b4.x); o[5] = (short)f2u(b4.y); o[6] = (short)f2u(b4.z); o[7] = (short)f2u(b4.w);
    *(short8*)(encb + i) = o;
    int s = i >> 14, b = (i >> 9) & 31, h = i & 511;
    *(short8*)(encc + (((size_t)b << 8) + s) * 512 + h) = o;
  } else if (id < 2176) {            // Wt: [We | Wfe] -> [1024][512]
    int f = id - 2048; int gx = f & 15, gy = f >> 4;
    int n0 = gx * 64, k0 = gy * 64;
    const float* src = (n0 < 512) ? (Wattn + 512 * 512) : Wfattn;
    int nb = (n0 < 512) ? n0 : n0 - 512;
    trans_tile(src, nb, k0, Wt, n0, 512, tile, t);
  } else if (id < 2240) {            // Wt2a: Wscore[1024:]^T [512][512]
    int f = id - 2176; int gx = f & 7, gy = f >> 3;
    trans_tile(Wscore + 1024 * 512, gx * 64, gy * 64, Wt2a, gx * 64, 512, tile, t);
  } else if (id < 2368) {            // Wt2b: Wscore[:1024]^T [512][1024]
    int f = id - 2240; int gx = f & 7, gy = f >> 3;
    trans_tile(Wscore, gx * 64, gy * 64, Wt2b, gx * 64, 1024, tile, t);
  } else if (id < 2432) {            // Wt3: Wfp1^T [512][512]
    int f = id - 2368; int gx = f & 7, gy = f >> 3;
    trans_tile(Wfp1, gx * 64, gy * 64, Wt3, gx * 64, 512, tile, t);
  } else if (id < 2560) {            // Wt4: [Wh^T | Wff^T] -> [1024][512]
    int f = id - 2432; int gx = f & 15, gy = f >> 4;
    int n0 = gx * 64, k0 = gy * 64;
    const float* src = (n0 < 512) ? Wattn : (Wfattn + 512 * 512);
    int nb = (n0 < 512) ? n0 : n0 - 512;
    trans_tile(src, nb, k0, Wt4, n0, 512, tile, t);
  } else if (id < 2816) {            // gates partials
    int f = id - 2560;
    int b = f >> 3, kc = f & 7;
    int hl = has_left[b];
    int k0 = kc * 128;
    float* o1 = gp1 + ((size_t)b * 8 + kc) * 512;
    float* o2 = gp2 + ((size_t)b * 8 + kc) * 512;
    if (!hl && kc >= 4) { o1[t] = 0.f; o1[t + 256] = 0.f; o2[t] = 0.f; o2[t + 256] = 0.f; return; }
    if (t < 128) {
      int k = k0 + t;
      x[t] = hl ? (k < 512 ? left[b * 512 + k] : node_emb[b * 512 + k - 512])
                : node_emb[b * 512 + k];
    }
    __syncthreads();
    const float* W1 = hl ? Wcr : Wcl;
    const float* W2 = hl ? Wcrg : Wclg;
    float a1 = 0.f, a2 = 0.f, a3 = 0.f, a4 = 0.f;
    for (int kk = 0; kk < 128; ++kk) {
      float xv = x[kk];
      const float* w1r = W1 + (size_t)(k0 + kk) * 512;
      const float* w2r = W2 + (size_t)(k0 + kk) * 512;
      a1 += xv * w1r[t]; a2 += xv * w1r[t + 256];
      a3 += xv * w2r[t]; a4 += xv * w2r[t + 256];
    }
    o1[t] = a1; o1[t + 256] = a2; o2[t] = a3; o2[t + 256] = a4;
  } else if (id < 3136) {            // out_embw + embb
    int f = id - 2816;
    #pragma unroll
    for (int rr = 0; rr < 2; ++rr) {
      int row = f * 2 + rr;
      int n = row % 20, b = row / 20;
      #pragma unroll
      for (int i = 0; i < 2; ++i) {
        int h = t + 256 * i;
        float v = (n < 4) ? emb_w[n * 512 + h] : num_pades[((size_t)b * 16 + n - 4) * 512 + h];
        out_embw[(size_t)row * 512 + h] = v;
        embb[(size_t)row * 512 + h] = f2u(v);
      }
    }
  } else {                           // leafb zero-pad rows 32..63
    int f = id - 3136;               // f < 8
    int base = 32 * 1024 + (f * 256 + t) * 16;
    short8 z8 = {0,0,0,0,0,0,0,0};
    *(short8*)(leafb + base) = z8;
    *(short8*)(leafb + base + 8) = z8;
  }
}

// ---------- GEMM device body ----------
template <int FM, int FN>
__device__ __forceinline__ void gemm_body(
    const u16* __restrict__ A, const u16* __restrict__ Bt,
    u16* __restrict__ C16, float* __restrict__ C32,
    int lda, int ldb, int ldc, int ksteps,
    int bm, int bn, int kbase, long zoff,
    u16* As, u16* Bs) {
  constexpr int BM = FM * 32, BN = FN * 32;
  const int tid = threadIdx.x;
  const int lane = tid & 63;
  const int wid = tid >> 6;
  const int wr = (wid >> 1) * (FM * 16);
  const int wc = (wid & 1) * (FN * 16);
  f32x4 acc[FM][FN];
  #pragma unroll
  for (int m = 0; m < FM; ++m)
    #pragma unroll
    for (int n = 0; n < FN; ++n)
      #pragma unroll
      for (int q = 0; q < 4; ++q) acc[m][n][q] = 0.f;

  const int kb = (lane >> 4) * 8;
  const int rr = lane & 15;
  for (int ks = 0; ks < ksteps; ++ks) {
    int k0 = kbase + ks * 32;
    #pragma unroll
    for (int it = 0; it < BM / 64; ++it) {
      int c = it * 256 + tid;
      gload16(A + (size_t)(bm + (c >> 2)) * lda + k0 + (c & 3) * 8, As + c * 8);
    }
    #pragma unroll
    for (int it = 0; it < BN / 64; ++it) {
      int c = it * 256 + tid;
      gload16(Bt + (size_t)(bn + (c >> 2)) * ldb + k0 + (c & 3) * 8, Bs + c * 8);
    }
    __syncthreads();
    short8 af[FM], bf[FN];
    #pragma unroll
    for (int m = 0; m < FM; ++m)
      af[m] = *(const short8*)(As + (wr + m * 16 + rr) * 32 + kb);
    #pragma unroll
    for (int n = 0; n < FN; ++n)
      bf[n] = *(const short8*)(Bs + (wc + n * 16 + rr) * 32 + kb);
    #pragma unroll
    for (int m = 0; m < FM; ++m)
      #pragma unroll
      for (int n = 0; n < FN; ++n)
        acc[m][n] = __builtin_amdgcn_mfma_f32_16x16x32_bf16(af[m], bf[n], acc[m][n], 0, 0, 0);
    __syncthreads();
  }
  int r0 = (lane >> 4) * 4, cc = lane & 15;
  #pragma unroll
  for (int m = 0; m < FM; ++m)
    #pragma unroll
    for (int n = 0; n < FN; ++n)
      #pragma unroll
      for (int q = 0; q < 4; ++q) {
        long row = bm + wr + m * 16 + r0 + q;
        long col = bn + wc + n * 16 + cc;
        if (C16) C16[zoff + row * ldc + col] = f2u(acc[m][n][q]);
        else     C32[zoff + row * ldc + col] = acc[m][n][q];
      }
}

// ---------- G1: EW GEMM (512) + CWFW GEMM (8) + T_emb GEMM (160, z=2) ----------
__global__ __launch_bounds__(256) void k_g1(
    const u16* __restrict__ encb, const u16* __restrict__ Wt, u16* __restrict__ EW,
    const u16* __restrict__ cnfs, const u16* __restrict__ Wt4, float* __restrict__ CWFW,
    const u16* __restrict__ embb, const u16* __restrict__ Wt2a, float* __restrict__ Tep) {
  __shared__ u16 As[128 * 32];
  __shared__ u16 Bs[128 * 32];
  int q = blockIdx.x;
  if (q < 512) {
    int x = q & 63, y = q >> 6;
    gemm_body<4, 4>(encb, Wt, EW, nullptr, 512, 512, 1024, 16, x * 128, y * 128, 0, 0, As, Bs);
  } else if (q < 520) {
    int y = q - 512;
    gemm_body<4, 4>(cnfs, Wt4, nullptr, CWFW, 512, 512, 1024, 16, 0, y * 128, 0, 0, As, Bs);
  } else {                      // T_emb: 640x512 @ K=512, z=2
    int q2 = q - 520;
    int x = q2 % 10, y = (q2 / 10) % 8, z = q2 / 80;
    gemm_body<2, 2>(embb, Wt2a, nullptr, Tep, 512, 512, 512, 8,
                    x * 64, y * 64, z * 8 * 32, (long)z * 327680, As, Bs);
  }
}

// ---------- tt: T_leaf (32) + T3 (256) GEMMs + op reduce (192) ----------
__global__ __launch_bounds__(256) void k_tt(
    const u16* __restrict__ leafb, const u16* __restrict__ Wt2b, float* __restrict__ Tlp,
    const u16* __restrict__ fctxb, const u16* __restrict__ Wt3, float* __restrict__ T3p,
    const float* __restrict__ leaf, const float* __restrict__ Wops,
    const float* __restrict__ bops, float* __restrict__ out_op) {
  __shared__ u16 As[64 * 32];
  __shared__ u16 Bs[64 * 32];
  __shared__ float red[4];
  int q = blockIdx.x;
  if (q < 32) {                  // T_leaf: 64x512 @ K=1024, z=4
    int y = q % 8, z = q / 8;
    gemm_body<2, 2>(leafb, Wt2b, nullptr, Tlp, 1024, 1024, 512, 8,
                    0, y * 64, z * 8 * 32, (long)z * 32768, As, Bs);
  } else if (q < 288) {          // T3: 512x512 @ K=512, z=4
    int q2 = q - 32;
    int x = q2 % 8, y = (q2 / 8) % 8, z = q2 / 64;
    gemm_body<2, 2>(fctxb, Wt3, nullptr, T3p, 512, 512, 512, 4,
                    x * 64, y * 64, z * 4 * 32, (long)z * 262144, As, Bs);
  } else {                       // op reduce
    int f = q - 288; int o = f % 6, b = f / 6;
    int t = threadIdx.x, w = t >> 6, lane = t & 63;
    float acc = 0.f;
    #pragma unroll
    for (int i = 0; i < 4; ++i) {
      int k = t + 256 * i;
      acc += leaf[b * 1024 + k] * Wops[(size_t)k * 6 + o];
    }
    for (int off = 32; off >= 1; off >>= 1) acc += __shfl_down(acc, off);
    if (lane == 0) red[w] = acc;
    __syncthreads();
    if (t == 0) out_op[b * 6 + o] = red[0] + red[1] + red[2] + red[3] + bops[o];
  }
}

// ---------- p2lite: finish gates -> cur_node/out_cn/cnfs; fs rows; zero pad ----------
__global__ __launch_bounds__(256) void k_p2(
    const float* __restrict__ gp1, const float* __restrict__ gp2,
    const int* __restrict__ has_left,
    const float* __restrict__ bcl, const float* __restrict__ bclg,
    const float* __restrict__ bcr, const float* __restrict__ bcrg,
    const float* __restrict__ fs,
    float* __restrict__ cur_node, float* __restrict__ out_cn, u16* __restrict__ cnfs) {
  int id = blockIdx.x, t = threadIdx.x;
  if (id < 32) {
    int b = id, hl = has_left[b];
    #pragma unroll
    for (int i = 0; i < 2; ++i) {
      int h = t + 256 * i;
      float s1 = 0.f, s2 = 0.f;
      #pragma unroll
      for (int c = 0; c < 8; ++c) {
        s1 += gp1[((size_t)b * 8 + c) * 512 + h];
        s2 += gp2[((size_t)b * 8 + c) * 512 + h];
      }
      float v = ftanh(s1 + (hl ? bcr[h] : bcl[h])) * fsig(s2 + (hl ? bcrg[h] : bclg[h]));
      cur_node[b * 512 + h] = v;
      out_cn[b * 512 + h] = v;
      cnfs[b * 512 + h] = f2u(v);
    }
  } else if (id < 48) {
    int r = id - 32;
    #pragma unroll
    for (int i = 0; i < 2; ++i) {
      int h = t + 256 * i;
      cnfs[id * 512 + h] = f2u(fs[r * 512 + h]);
    }
  } else {
    #pragma unroll
    for (int i = 0; i < 2; ++i) cnfs[id * 512 + t + 256 * i] = 0;
  }
}

// ---------- en + fen fused (mask-skip, shared sFW reads across s-pair) ----------
__global__ __launch_bounds__(256) void k_enfen(
    const u16* __restrict__ EW, const float* __restrict__ CWFW,
    const float* __restrict__ battn, const float* __restrict__ bfattn,
    const float* __restrict__ wattn_s, const float* __restrict__ battn_s,
    const float* __restrict__ wfattn_s, const float* __restrict__ bfattn_s,
    const int* __restrict__ seq_mask, float* __restrict__ en, float* __restrict__ fen) {
  __shared__ float sFW[16 * 512];
  __shared__ float swf[512], swa[512], scw[512];
  int bid = blockIdx.x;          // 1024 = 32 b * 32 s-chunks
  int b = bid >> 5;
  int s0 = (bid & 31) * 8;
  int t = threadIdx.x;
  #pragma unroll
  for (int q = 0; q < 32; ++q) {
    int flat = q * 256 + t;
    int r = flat >> 9, h = flat & 511;
    sFW[flat] = CWFW[(size_t)(32 + r) * 1024 + 512 + h] + bfattn[h];
  }
  swf[t] = wfattn_s[t]; swf[256 + t] = wfattn_s[256 + t];
  swa[t] = wattn_s[t];  swa[256 + t] = wattn_s[256 + t];
  scw[t] = CWFW[(size_t)b * 1024 + t] + battn[t];
  scw[256 + t] = CWFW[(size_t)b * 1024 + 256 + t] + battn[256 + t];
  __syncthreads();
  int w = t >> 6, lane = t & 63;
  int sA = s0 + w * 2, sB = sA + 1;
  int mA = seq_mask[b * 256 + sA], mB = seq_mask[b * 256 + sB];
  if (mA && mB) {
    if (lane == 0) {
      en[b * 256 + sA] = NEG; en[b * 256 + sB] = NEG;
      for (int r = 0; r < 16; ++r) {
        fen[((size_t)b * 16 + r) * 256 + sA] = NEG;
        fen[((size_t)b * 16 + r) * 256 + sB] = NEG;
      }
    }
    return;
  }
  const u16* ewA = EW + (size_t)(sA * 32 + b) * 1024;
  const u16* ewB = EW + (size_t)(sB * 32 + b) * 1024;
  float ewfA[8], ewfB[8], wfv[8];
  float accA = 0.f, accB = 0.f;
  #pragma unroll
  for (int i = 0; i < 8; ++i) {
    int h = lane + 64 * i;
    float cw = scw[h], wa = swa[h];
    accA += ptanh(cw + bf2f(ewA[h])) * wa;
    accB += ptanh(cw + bf2f(ewB[h])) * wa;
    ewfA[i] = bf2f(ewA[512 + h]);
    ewfB[i] = bf2f(ewB[512 + h]);
    wfv[i] = swf[h];
  }
  for (int o = 32; o >= 1; o >>= 1) {
    accA += __shfl_down(accA, o);
    accB += __shfl_down(accB, o);
  }
  if (lane == 0) {
    en[b * 256 + sA] = mA ? NEG : (accA + battn_s[0]);
    en[b * 256 + sB] = mB ? NEG : (accB + battn_s[0]);
  }
  for (int r = 0; r < 16; ++r) {
    float a0 = 0.f, a1 = 0.f;
    #pragma unroll
    for (int i = 0; i < 8; ++i) {
      int h = lane + 64 * i;
      float fwv = sFW[r * 512 + h];
      a0 += ptanh(fwv + ewfA[i]) * wfv[i];
      a1 += ptanh(fwv + ewfB[i]) * wfv[i];
    }
    for (int o = 32; o >= 1; o >>= 1) {
      a0 += __shfl_down(a0, o);
      a1 += __shfl_down(a1, o);
    }
    if (lane == 0) {
      fen[((size_t)b * 16 + r) * 256 + sA] = mA ? NEG : (a0 + bfattn_s[0]);
      fen[((size_t)b * 16 + r) * 256 + sB] = mB ? NEG : (a1 + bfattn_s[0]);
    }
  }
}

// ---------- softmaxes + contexts, j-paired, contiguous encc ----------
__global__ __launch_bounds__(512) void k_ctxall(
    const float* __restrict__ en, const float* __restrict__ fen,
    const u16* __restrict__ encc, const float* __restrict__ cur_node,
    float* __restrict__ out_ctx, float* __restrict__ leaf, u16* __restrict__ fctxb,
    u16* __restrict__ leafb) {
  int br = blockIdx.x;           // 288 = 32 * 9
  int b = br / 9, k = br % 9;
  int t = threadIdx.x;
  __shared__ float red[512];
  __shared__ float sa0[256], sa1[256];
  float xe = (t < 256) ? en[b * 256 + t] : NEG;
  red[t] = xe; __syncthreads();
  for (int o = 256; o > 0; o >>= 1) { if (t < o) red[t] = fmaxf(red[t], red[t + o]); __syncthreads(); }
  float m = red[0]; __syncthreads();
  float ee = (t < 256) ? __expf(xe - m) : 0.f;
  red[t] = ee; __syncthreads();
  for (int o = 256; o > 0; o >>= 1) { if (t < o) red[t] += red[t + o]; __syncthreads(); }
  float attn_v = ee / red[0];
  __syncthreads();
  const u16* eb = encc + (size_t)b * 131072;
  if (k < 8) {
    #pragma unroll
    for (int p = 0; p < 2; ++p) {
      int j = k + p * 8;
      float xf = (t < 256) ? fen[((size_t)b * 16 + j) * 256 + t] : NEG;
      red[t] = xf; __syncthreads();
      for (int o = 256; o > 0; o >>= 1) { if (t < o) red[t] = fmaxf(red[t], red[t + o]); __syncthreads(); }
      float mf = red[0]; __syncthreads();
      float ef = (t < 256) ? __expf(xf - mf) : 0.f;
      red[t] = ef; __syncthreads();
      for (int o = 256; o > 0; o >>= 1) { if (t < o) red[t] += red[t + o]; __syncthreads(); }
      float coef = ef / red[0] + 0.2f * attn_v;
      __syncthreads();
      if (t < 256) { if (p == 0) sa0[t] = coef; else sa1[t] = coef; }
    }
    __syncthreads();
    int h = t;
    float acc0 = 0.f, acc1 = 0.f;
    #pragma unroll 8
    for (int s = 0; s < 256; ++s) {
      float ev = bf2f(eb[(size_t)s * 512 + h]);
      acc0 += sa0[s] * ev;
      acc1 += sa1[s] * ev;
    }
    fctxb[((size_t)b * 16 + k) * 512 + h] = f2u(acc0);
    fctxb[((size_t)b * 16 + k + 8) * 512 + h] = f2u(acc1);
  } else {
    if (t < 256) sa0[t] = attn_v;
    __syncthreads();
    int h = t;
    float acc = 0.f;
    #pragma unroll 8
    for (int s = 0; s < 256; ++s)
      acc += sa0[s] * bf2f(eb[(size_t)s * 512 + h]);
    float cn = cur_node[b * 512 + h];
    out_ctx[b * 512 + h] = acc;
    leaf[b * 1024 + 512 + h] = acc;
    leaf[b * 1024 + h] = cn;
    leafb[b * 1024 + h] = f2u(cn);
    leafb[b * 1024 + 512 + h] = f2u(acc);
  }
}

// ---------- epilogue: num_score + formula_prob ----------
__global__ __launch_bounds__(256) void k_epi(
    const float* __restrict__ Tep, const float* __restrict__ Tlp,
    const float* __restrict__ bscore,
    const float* __restrict__ wscore_s, const int* __restrict__ mask_nums,
    float* __restrict__ out_ns,
    const float* __restrict__ T3p, const float* __restrict__ bfp1,
    const float* __restrict__ Wfp2, const float* __restrict__ bfp2,
    float* __restrict__ out_fp) {
  int id = blockIdx.x, t = threadIdx.x;
  int w = t >> 6, lane = t & 63;
  __shared__ float red[16];
  if (id < 640) {
    int row = id;
    int b = row / 20;
    float acc = 0.f;
    #pragma unroll
    for (int i = 0; i < 2; ++i) {
      int h = t + 256 * i;
      float tv = bscore[h];
      #pragma unroll
      for (int z = 0; z < 2; ++z) tv += Tep[(size_t)z * 327680 + (size_t)row * 512 + h];
      #pragma unroll
      for (int z = 0; z < 4; ++z) tv += Tlp[(size_t)z * 32768 + (size_t)b * 512 + h];
      acc += ftanh(tv) * wscore_s[h];
    }
    for (int o = 32; o >= 1; o >>= 1) acc += __shfl_down(acc, o);
    if (lane == 0) red[w] = acc;
    __syncthreads();
    if (t == 0) out_ns[row] = mask_nums[row] ? NEG : (red[0] + red[1] + red[2] + red[3]);
  } else {
    int b = id - 640;
    #pragma unroll
    for (int j2 = 0; j2 < 4; ++j2) {
      int j = w * 4 + j2;
      int row = b * 16 + j;
      float acc = 0.f;
      #pragma unroll
      for (int i = 0; i < 8; ++i) {
        int h = lane + 64 * i;
        float v = bfp1[h];
        #pragma unroll
        for (int z = 0; z < 4; ++z) v += T3p[(size_t)z * 262144 + (size_t)row * 512 + h];
        acc += ftanh(v) * Wfp2[h];
      }
      for (int o = 32; o >= 1; o >>= 1) acc += __shfl_down(acc, o);
      if (lane == 0) red[j] = acc + bfp2[0];
    }
    __syncthreads();
    if (t < 16) {
      float xx = red[t];
      float mm = xx;
      for (int o = 8; o >= 1; o >>= 1) mm = fmaxf(mm, __shfl_xor(mm, o, 16));
      float e = __expf(xx - mm);
      float s2 = e;
      for (int o = 8; o >= 1; o >>= 1) s2 += __shfl_xor(s2, o, 16);
      out_fp[b * 16 + t] = e / s2;
    }
  }
}

extern "C" void kernel_launch(void* const* d_in, const int* in_sizes, int n_in,
                              void* d_out, int out_size, void* d_ws, size_t ws_size,
                              hipStream_t stream) {
  const float* node_emb  = (const float*)d_in[0];
  const float* left      = (const float*)d_in[1];
  const float* enc       = (const float*)d_in[2];
  const float* num_pades = (const float*)d_in[3];
  const float* fs        = (const float*)d_in[4];
  const int*   has_left  = (const int*)d_in[5];
  const int*   seq_mask  = (const int*)d_in[6];
  const int*   mask_nums = (const int*)d_in[7];
  const float* emb_w     = (const float*)d_in[8];
  const float* Wcl  = (const float*)d_in[9];
  const float* bcl  = (const float*)d_in[10];
  const float* Wclg = (const float*)d_in[11];
  const float* bclg = (const float*)d_in[12];
  const float* Wcr  = (const float*)d_in[13];
  const float* bcr  = (const float*)d_in[14];
  const float* Wcrg = (const float*)d_in[15];
  const float* bcrg = (const float*)d_in[16];
  const float* Wops = (const float*)d_in[17];
  const float* bops = (const float*)d_in[18];
  const float* Wattn   = (const float*)d_in[19];
  const float* battn   = (const float*)d_in[20];
  const float* wattn_s = (const float*)d_in[21];
  const float* battn_s = (const float*)d_in[22];
  const float* Wfattn   = (const float*)d_in[23];
  const float* bfattn   = (const float*)d_in[24];
  const float* wfattn_s = (const float*)d_in[25];
  const float* bfattn_s = (const float*)d_in[26];
  const float* Wscore   = (const float*)d_in[27];
  const float* bscore   = (const float*)d_in[28];
  const float* wscore_s = (const float*)d_in[29];
  const float* Wfp1 = (const float*)d_in[30];
  const float* bfp1 = (const float*)d_in[31];
  const float* Wfp2 = (const float*)d_in[32];
  const float* bfp2 = (const float*)d_in[33];

  float* out = (float*)d_out;
  float* out_ns   = out + 0;
  float* out_op   = out + 640;
  float* out_cn   = out + 832;
  float* out_ctx  = out + 17216;
  float* out_embw = out + 33600;
  float* out_fp   = out + 361280;

  // ws is 256 MiB
  uint8_t* wsb = (uint8_t*)d_ws;
  u16*   encb = (u16*)(wsb + 0);              //  8,388,608
  u16*   Wt   = (u16*)(wsb + 8388608);        //  1,048,576
  u16*   Wt2a = (u16*)(wsb + 9437184);        //    524,288
  u16*   Wt2b = (u16*)(wsb + 9961472);        //  1,048,576
  u16*   Wt3  = (u16*)(wsb + 11010048);       //    524,288
  u16*   Wt4  = (u16*)(wsb + 11534336);       //  1,048,576
  u16*   EW   = (u16*)(wsb + 12582912);       // 16,777,216
  u16*   embb = (u16*)(wsb + 29360128);       //    655,360
  u16*   leafb= (u16*)(wsb + 30015488);       //    131,072
  u16*   cnfs = (u16*)(wsb + 30146560);       //    131,072
  float* CWFW = (float*)(wsb + 30277632);     //    524,288
  float* Tep  = (float*)(wsb + 30801920);     //  5,242,880 (z=2 uses 2.5MB)
  float* Tlp  = (float*)(wsb + 36044800);     //    524,288
  float* T3p  = (float*)(wsb + 36569088);     //  4,194,304
  float* fb   = (float*)(wsb + 40763392);
  float* cur_node = fb + 0;          // 16384
  float* en   = fb + 16384;          // 8192
  float* fen  = fb + 24576;          // 131072
  float* leaf = fb + 155648;         // 32768
  u16*   fctxb= (u16*)(fb + 188416); // 262144 u16
  float* gp1  = fb + 319488;         // 131072
  float* gp2  = fb + 450560;         // 131072
  u16*   encc = (u16*)(wsb + 45088768);       //  8,388,608

  // 1. mega prep (inputs only)
  k_prep1<<<3144, 256, 0, stream>>>(enc, encb, encc, Wattn, Wfattn, Wt, Wscore, Wt2a, Wt2b,
                                    Wfp1, Wt3, Wt4,
                                    node_emb, left, has_left, Wcl, Wclg, Wcr, Wcrg,
                                    gp1, gp2, emb_w, num_pades, out_embw, embb, leafb);
  // 2. finish gates -> cur_node + cnfs
  k_p2<<<128, 256, 0, stream>>>(gp1, gp2, has_left, bcl, bclg, bcr, bcrg, fs,
                                cur_node, out_cn, cnfs);
  // 3. G1: EW GEMM + CWFW GEMM + T_emb GEMM (z=2, co-scheduled)
  k_g1<<<680, 256, 0, stream>>>(encb, Wt, EW, cnfs, Wt4, CWFW, embb, Wt2a, Tep);
  // 4. attention scores (mask-skip, shared sFW reads)
  k_enfen<<<1024, 256, 0, stream>>>(EW, CWFW, battn, bfattn, wattn_s, battn_s,
                                    wfattn_s, bfattn_s, seq_mask, en, fen);
  // 5. softmaxes + contexts, j-paired, contiguous encc
  k_ctxall<<<288, 512, 0, stream>>>(en, fen, encc, cur_node, out_ctx, leaf, fctxb, leafb);
  // 6. T_leaf + T3 GEMMs + op reduce
  k_tt<<<480, 256, 0, stream>>>(leafb, Wt2b, Tlp, fctxb, Wt3, T3p,
                                leaf, Wops, bops, out_op);
  // 7. epilogue: ns + ffprob
  k_epi<<<672, 256, 0, stream>>>(Tep, Tlp, bscore, wscore_s, mask_nums, out_ns,
                                 T3p, bfp1, Wfp2, bfp2, out_fp);
}